// Round 10
// baseline (190.652 us; speedup 1.0000x reference)
//
#include <hip/hip_runtime.h>

// Forbid FMA contraction EVERYWHERE: distances must be bit-identical to
// numpy's unfused ((dx*dx + dy*dy) + dz*dz) in main loop AND fallback.
#pragma clang fp contract(off)

typedef unsigned long long u64;
typedef unsigned int u32;
typedef unsigned short u16;
typedef float f32x2 __attribute__((ext_vector_type(2)));

#define BB 8
#define LL 2048
#define MM 4096
#define KK 25
#define WPB 16           // waves (queries) per block
#define TPB 1024
#define CAP 3072         // compacted-valid capacity (V ~ 2048 +- 32; P(V>CAP)~0)
#define SENT  0xFFFFFFFFFFFFFFFFull
#define SENTH 0xFFFFFFFFu   // exhausted marker for value words (> inf-bits+1)

// Wave64 min-reduce -> wave-uniform scalar (proven round-9 DPP ladder).
static __device__ __forceinline__ u32 wave_min_u32(u32 x) {
    u32 t;
    t = (u32)__builtin_amdgcn_update_dpp(0, (int)x, 0xB1, 0xF, 0xF, true);   // xor1
    x = t < x ? t : x;
    t = (u32)__builtin_amdgcn_update_dpp(0, (int)x, 0x4E, 0xF, 0xF, true);   // xor2
    x = t < x ? t : x;
    t = (u32)__builtin_amdgcn_update_dpp(0, (int)x, 0x141, 0xF, 0xF, true);  // half-row mirror
    x = t < x ? t : x;
    t = (u32)__builtin_amdgcn_update_dpp(0, (int)x, 0x140, 0xF, 0xF, true);  // row mirror
    x = t < x ? t : x;
    t = (u32)__builtin_amdgcn_update_dpp((int)x, (int)x, 0x142, 0xF, 0xF, false); // row_bcast15
    x = t < x ? t : x;
    t = (u32)__builtin_amdgcn_update_dpp((int)x, (int)x, 0x143, 0xF, 0xF, false); // row_bcast31
    x = t < x ? t : x;
    return (u32)__builtin_amdgcn_readlane((int)x, 63);
}

// ===========================================================================
// ROUND 21 = ROUND-20 MEASUREMENT ROUND RESUBMITTED VERBATIM.
// Round-20 died at container level (same signature as round-4's infra flake;
// audit found no OOB/barrier/asm fault — see journal). Two dispatches:
//  * knn_mainonly (grid 4096 = 4x residency rounds): r19 staging + main loop
//    + key formation, asm-volatile keep-alives, NO global writes. Isolates
//    the staging+main share: M = (json_dur - 57 - F)/4, or read directly if
//    it tops the counter table.
//  * knn_kernel (grid 1024): r19 VERBATIM -> d_out (correctness + F).
// Rationale: VALU-busy TIME was invariant (~32us) across r17/r18/r19 despite
// ~25% static instruction cuts — the cost model is wrong; measure, don't
// guess. Decision rule: extraction-dominant (M ~ 10-14us) -> rewrite the
// serial 25-pop ladder next; main-dominant (M ~ 25-30us) -> restructure the
// main loop next.
// ===========================================================================

__global__ void __launch_bounds__(TPB, 8) knn_mainonly(
    const float* __restrict__ CB, const float* __restrict__ maskA,
    const float* __restrict__ Y, const int* __restrict__ Yt,
    const int* __restrict__ Ym)
{
    __shared__ __align__(16) float sX[CAP];
    __shared__ __align__(16) float sY[CAP];
    __shared__ __align__(16) float sZ[CAP];
    __shared__ u16 sP16[CAP];
    __shared__ u16 sMidx[64];
    __shared__ int sWinc[16];
    __shared__ int sWbase[16];
    __shared__ int sVtot;

    const int tid  = threadIdx.x;
    const int lane = tid & 63;
    const int wv   = tid >> 6;
    const int blk  = blockIdx.x;
    const int b    = (blk >> 7) & 7;  // wraps 4x over the 8 batches
    const int qg   = blk & 127;

    const float* Yb  = Y  + (size_t)b * MM * 3;
    const int*   Ymb = Ym + (size_t)b * MM;

    const int p0 = tid << 2;
    const float4 f0 = *(const float4*)(Yb + 3 * p0);
    const float4 f1 = *(const float4*)(Yb + 3 * p0 + 4);
    const float4 f2 = *(const float4*)(Yb + 3 * p0 + 8);
    const int4   m4 = *(const int4*)(Ymb + p0);
    const int v0 = (m4.x != 0), v1 = (m4.y != 0), v2 = (m4.z != 0), v3 = (m4.w != 0);
    const int cnt = v0 + v1 + v2 + v3;

    int inc = cnt;
#pragma unroll
    for (int off = 1; off < 64; off <<= 1) {
        const int t = __shfl_up(inc, off, 64);
        if (lane >= off) inc += t;
    }
    if (lane == 63) sWinc[wv] = inc;
    __syncthreads();
    if (tid < 16) {
        const int x = sWinc[tid];
        int ix = x;
#pragma unroll
        for (int off = 1; off < 16; off <<= 1) {
            const int t = __shfl_up(ix, off, 16);
            if (tid >= off) ix += t;
        }
        sWbase[tid] = ix - x;
        if (tid == 15) sVtot = ix;
    }
    __syncthreads();

    {
        int bs = sWbase[wv] + inc - cnt;
        int mb = p0 - bs;
        if (v0) { sX[bs]=f0.x; sY[bs]=f0.y; sZ[bs]=f0.z; sP16[bs]=(u16)(p0+0); bs++; }
        else    { if (mb < 64) sMidx[mb] = (u16)(p0 + 0); mb++; }
        if (v1) { sX[bs]=f0.w; sY[bs]=f1.x; sZ[bs]=f1.y; sP16[bs]=(u16)(p0+1); bs++; }
        else    { if (mb < 64) sMidx[mb] = (u16)(p0 + 1); mb++; }
        if (v2) { sX[bs]=f1.z; sY[bs]=f1.w; sZ[bs]=f2.x; sP16[bs]=(u16)(p0+2); bs++; }
        else    { if (mb < 64) sMidx[mb] = (u16)(p0 + 2); mb++; }
        if (v3) { sX[bs]=f2.y; sY[bs]=f2.z; sZ[bs]=f2.w; sP16[bs]=(u16)(p0+3); bs++; }
        else    { if (mb < 64) sMidx[mb] = (u16)(p0 + 3); mb++; }
    }
    const int V  = sVtot;
    const int NJ = (V + 127) >> 7;
    for (int c = V + tid; c < (NJ << 7); c += TPB) {
        sX[c] = __builtin_inff(); sY[c] = 0.0f; sZ[c] = 0.0f; sP16[c] = 4095;
    }
    __syncthreads();

    const int l = qg * WPB + wv;
    const int q = b * LL + l;

    if (maskA[q] == 0.0f) return;       // stub: NO writes anywhere

    const float cx = CB[3 * q + 0];
    const float cy = CB[3 * q + 1];
    const float cz = CB[3 * q + 2];

    float v1f = 3.0e38f, v2f = 3.0e38f, v3f = 3.0e38f, v4f = 3.0e38f;
    u32 J = 0u;
    const u32 SEL1 = 0x06050400u;
    const u32 SEL2 = 0x06050004u;
    const u32 SEL3 = 0x06000504u;
    const u32 SEL4 = 0x00060504u;
    auto ins = [&](float v, u32 id) {
        const bool c1 = v < v1f, c2 = v < v2f, c3 = v < v3f, c4 = v < v4f;
        const u32 sel = c1 ? SEL1 : (c2 ? SEL2 : (c3 ? SEL3 : SEL4));
        const u32 Jp  = __builtin_amdgcn_perm(J, id, sel);
        const float n2 = __builtin_amdgcn_fmed3f(v, v1f, v2f);
        const float n3 = __builtin_amdgcn_fmed3f(v, v2f, v3f);
        const float n4 = __builtin_amdgcn_fmed3f(v, v3f, v4f);
        v1f = fminf(v, v1f);
        v2f = n2; v3f = n3; v4f = n4;
        J = c4 ? Jp : J;
    };

    const f32x2 cxx = {cx, cx}, cyy = {cy, cy}, czz = {cz, cz};
#pragma unroll 4
    for (int j = 0; j < NJ; ++j) {
        const int base = (j << 7) + (lane << 1);
        const f32x2 xp = *(const f32x2*)&sX[base];
        const f32x2 yp = *(const f32x2*)&sY[base];
        const f32x2 zp = *(const f32x2*)&sZ[base];
        const f32x2 dx = cxx - xp;
        const f32x2 dy = cyy - yp;
        const f32x2 dz = czz - zp;
        const f32x2 dsq = (dx * dx + dy * dy) + dz * dz;
        ins(dsq.x, (u32)(j << 1));
        ins(dsq.y, (u32)((j << 1) | 1));
    }

    auto slotof = [&](u32 id) -> u32 {
        return ((id >> 1) << 7) | (u32)(lane << 1) | (id & 1u);
    };

    u32 h1 = __float_as_uint(v1f) + 1u;
    u32 h2 = __float_as_uint(v2f) + 1u;
    u32 h3 = __float_as_uint(v3f) + 1u;
    u32 h4 = __float_as_uint(v4f) + 1u;
    u64 lref = ((u64)h4 << 32) | slotof((J >> 24) & 0xFFu);
    const u32 lrl = (u32)lref, lrh = (u32)(lref >> 32);

    // keep-alive sinks (rule #17): no memory traffic, defeats DCE
    asm volatile("" :: "v"(h1), "v"(h2), "v"(h3), "v"(h4), "v"(J),
                       "v"(lrl), "v"(lrh));
}

// ---------------------------------------------------------------------------
// Real kernel: ROUND 19 VERBATIM (48.0us, absmax 0)
// ---------------------------------------------------------------------------
__global__ void __launch_bounds__(TPB, 8) knn_kernel(
    const float* __restrict__ CB, const float* __restrict__ maskA,
    const float* __restrict__ Y, const int* __restrict__ Yt,
    const int* __restrict__ Ym, float* __restrict__ out)
{
    __shared__ __align__(16) float sX[CAP];
    __shared__ __align__(16) float sY[CAP];
    __shared__ __align__(16) float sZ[CAP];
    __shared__ u16 sP16[CAP];
    __shared__ u16 sMidx[64];
    __shared__ int sWinc[16];
    __shared__ int sWbase[16];
    __shared__ int sVtot;
    __shared__ u32 sWinV[WPB][KK];
    __shared__ u16 sWinS[WPB][KK];

    const int tid  = threadIdx.x;
    const int lane = tid & 63;
    const int wv   = tid >> 6;
    const int blk  = blockIdx.x;
    const int b    = blk >> 7;
    const int qg   = blk & 127;

    const float* Yb  = Y  + (size_t)b * MM * 3;
    const int*   Ymb = Ym + (size_t)b * MM;
    const int*   Ytb = Yt + (size_t)b * MM;

    const int p0 = tid << 2;
    const float4 f0 = *(const float4*)(Yb + 3 * p0);
    const float4 f1 = *(const float4*)(Yb + 3 * p0 + 4);
    const float4 f2 = *(const float4*)(Yb + 3 * p0 + 8);
    const int4   m4 = *(const int4*)(Ymb + p0);
    const int v0 = (m4.x != 0), v1 = (m4.y != 0), v2 = (m4.z != 0), v3 = (m4.w != 0);
    const int cnt = v0 + v1 + v2 + v3;

    int inc = cnt;
#pragma unroll
    for (int off = 1; off < 64; off <<= 1) {
        const int t = __shfl_up(inc, off, 64);
        if (lane >= off) inc += t;
    }
    if (lane == 63) sWinc[wv] = inc;
    __syncthreads();
    if (tid < 16) {
        const int x = sWinc[tid];
        int ix = x;
#pragma unroll
        for (int off = 1; off < 16; off <<= 1) {
            const int t = __shfl_up(ix, off, 16);
            if (tid >= off) ix += t;
        }
        sWbase[tid] = ix - x;
        if (tid == 15) sVtot = ix;
    }
    __syncthreads();

    {
        int bs = sWbase[wv] + inc - cnt;
        int mb = p0 - bs;
        if (v0) { sX[bs]=f0.x; sY[bs]=f0.y; sZ[bs]=f0.z; sP16[bs]=(u16)(p0+0); bs++; }
        else    { if (mb < 64) sMidx[mb] = (u16)(p0 + 0); mb++; }
        if (v1) { sX[bs]=f0.w; sY[bs]=f1.x; sZ[bs]=f1.y; sP16[bs]=(u16)(p0+1); bs++; }
        else    { if (mb < 64) sMidx[mb] = (u16)(p0 + 1); mb++; }
        if (v2) { sX[bs]=f1.z; sY[bs]=f1.w; sZ[bs]=f2.x; sP16[bs]=(u16)(p0+2); bs++; }
        else    { if (mb < 64) sMidx[mb] = (u16)(p0 + 2); mb++; }
        if (v3) { sX[bs]=f2.y; sY[bs]=f2.z; sZ[bs]=f2.w; sP16[bs]=(u16)(p0+3); bs++; }
        else    { if (mb < 64) sMidx[mb] = (u16)(p0 + 3); mb++; }
    }
    const int V  = sVtot;
    const int NJ = (V + 127) >> 7;
    for (int c = V + tid; c < (NJ << 7); c += TPB) {
        sX[c] = __builtin_inff(); sY[c] = 0.0f; sZ[c] = 0.0f; sP16[c] = 4095;
    }
    __syncthreads();

    const int l = qg * WPB + wv;
    const int q = b * LL + l;

    float* out_y = out;
    float* out_t = out + (size_t)BB * LL * KK * 3;
    float* out_m = out_t + (size_t)BB * LL * KK;
    float* out_d = out_m + (size_t)BB * LL * KK;

    if (maskA[q] == 0.0f) {
        if (lane < KK) {
            const int p = lane;
            const size_t o = (size_t)q * KK + lane;
            out_y[3 * o + 0] = Yb[3 * p + 0];
            out_y[3 * o + 1] = Yb[3 * p + 1];
            out_y[3 * o + 2] = Yb[3 * p + 2];
            out_t[o] = (float)Ytb[p];
            out_m[o] = (float)Ymb[p];
            if (lane == 0) out_d[q] = sqrtf(1000.0f);
        }
        return;
    }

    const float cx = CB[3 * q + 0];
    const float cy = CB[3 * q + 1];
    const float cz = CB[3 * q + 2];

    float v1f = 3.0e38f, v2f = 3.0e38f, v3f = 3.0e38f, v4f = 3.0e38f;
    u32 J = 0u;
    const u32 SEL1 = 0x06050400u;
    const u32 SEL2 = 0x06050004u;
    const u32 SEL3 = 0x06000504u;
    const u32 SEL4 = 0x00060504u;
    auto ins = [&](float v, u32 id) {
        const bool c1 = v < v1f, c2 = v < v2f, c3 = v < v3f, c4 = v < v4f;
        const u32 sel = c1 ? SEL1 : (c2 ? SEL2 : (c3 ? SEL3 : SEL4));
        const u32 Jp  = __builtin_amdgcn_perm(J, id, sel);
        const float n2 = __builtin_amdgcn_fmed3f(v, v1f, v2f);
        const float n3 = __builtin_amdgcn_fmed3f(v, v2f, v3f);
        const float n4 = __builtin_amdgcn_fmed3f(v, v3f, v4f);
        v1f = fminf(v, v1f);
        v2f = n2; v3f = n3; v4f = n4;
        J = c4 ? Jp : J;
    };

    const f32x2 cxx = {cx, cx}, cyy = {cy, cy}, czz = {cz, cz};
#pragma unroll 4
    for (int j = 0; j < NJ; ++j) {
        const int base = (j << 7) + (lane << 1);
        const f32x2 xp = *(const f32x2*)&sX[base];
        const f32x2 yp = *(const f32x2*)&sY[base];
        const f32x2 zp = *(const f32x2*)&sZ[base];
        const f32x2 dx = cxx - xp;
        const f32x2 dy = cyy - yp;
        const f32x2 dz = czz - zp;
        const f32x2 dsq = (dx * dx + dy * dy) + dz * dz;
        ins(dsq.x, (u32)(j << 1));
        ins(dsq.y, (u32)((j << 1) | 1));
    }

    auto slotof = [&](u32 id) -> u32 {
        return ((id >> 1) << 7) | (u32)(lane << 1) | (id & 1u);
    };

    u32 h1 = __float_as_uint(v1f) + 1u;
    u32 h2 = __float_as_uint(v2f) + 1u;
    u32 h3 = __float_as_uint(v3f) + 1u;
    u32 h4 = __float_as_uint(v4f) + 1u;
    u64 lref = ((u64)h4 << 32) | slotof((J >> 24) & 0xFFu);

#pragma unroll 1
    for (int it = 0; it < KK; ++it) {
        if (it >= 4 && __any(h1 == SENTH)) {
            const bool need = (h1 == SENTH);
            u64 found = SENT;
            const int NI = NJ << 1;
#pragma unroll 4
            for (int id = 0; id < NI; ++id) {
                const u32 s = slotof((u32)id);
                const float dx = cx - sX[s];
                const float dy = cy - sY[s];
                const float dz = cz - sZ[s];
                const float v = (dx * dx + dy * dy) + dz * dz;
                const u64 key = ((u64)(__float_as_uint(v) + 1u) << 32) | s;
                if (key > lref && key < found) found = key;
            }
            if (need) {
                const u32 s = (u32)found & 0xFFFFu;
                h1 = (u32)(found >> 32);
                J = (J & ~0xFFu) | (((s >> 7) << 1) | (s & 1u));
                lref = found;
            }
        }
        const u32 bv = wave_min_u32(h1);
        const u64 ball = __ballot(h1 == bv);
        bool win = (h1 == bv);
        if (__popcll(ball) != 1) {
            const u32 vl = slotof(J & 0xFFu);
            u32 cp = win ? vl : 0xFFFFFFFFu;
#pragma unroll
            for (int off = 32; off; off >>= 1) {
                const u32 o = __shfl_xor(cp, off, 64);
                cp = (o < cp) ? o : cp;
            }
            win = win && (vl == cp);
        }
        if (win) {
            sWinV[wv][it] = h1;
            sWinS[wv][it] = (u16)slotof(J & 0xFFu);
            h1 = h2; h2 = h3; h3 = h4; h4 = SENTH;
            J >>= 8;
        }
    }

    u32 mvh = 0; u32 mslot = 0;
    if (lane < KK) { mvh = sWinV[wv][lane]; mslot = sWinS[wv][lane]; }
    const bool less = (lane < KK) && (mvh < 0x447A0001u);
    const int nless = __popcll(__ballot(less));
    if (lane < KK) {
        int p; float val, mflag;
        if (lane < nless) {
            p = (int)sP16[mslot];
            val = __uint_as_float(mvh - 1u);
            mflag = 1.0f;
        } else {
            p = (int)sMidx[lane - nless];
            val = 1000.0f;
            mflag = 0.0f;
        }
        const size_t o = (size_t)q * KK + lane;
        out_y[3 * o + 0] = Yb[3 * p + 0];
        out_y[3 * o + 1] = Yb[3 * p + 1];
        out_y[3 * o + 2] = Yb[3 * p + 2];
        out_t[o] = (float)Ytb[p];
        out_m[o] = mflag;
        if (lane == 0) out_d[q] = sqrtf(val);
    }
}

extern "C" void kernel_launch(void* const* d_in, const int* in_sizes, int n_in,
                              void* d_out, int out_size, void* d_ws, size_t ws_size,
                              hipStream_t stream) {
    const float* CB   = (const float*)d_in[0];
    const float* mask = (const float*)d_in[1];
    const float* Y    = (const float*)d_in[2];
    const int*   Yt   = (const int*)d_in[3];
    const int*   Ym   = (const int*)d_in[4];
    float* out = (float*)d_out;

    // measurement stub: staging+main only, 4x residency rounds, no writes
    hipLaunchKernelGGL(knn_mainonly, dim3(4096), dim3(TPB), 0, stream,
                       CB, mask, Y, Yt, Ym);
    // real kernel (r19 verbatim)
    hipLaunchKernelGGL(knn_kernel, dim3(BB * LL / WPB), dim3(TPB), 0, stream,
                       CB, mask, Y, Yt, Ym, out);
}

// Round 11
// 107.627 us; speedup vs baseline: 1.7714x; 1.7714x over previous
//
#include <hip/hip_runtime.h>

// Forbid FMA contraction EVERYWHERE: distances must be bit-identical to
// numpy's unfused ((dx*dx + dy*dy) + dz*dz) in main loop AND fallback.
#pragma clang fp contract(off)

typedef unsigned long long u64;
typedef unsigned int u32;
typedef unsigned short u16;
typedef float f32x2 __attribute__((ext_vector_type(2)));

#define BB 8
#define LL 2048
#define MM 4096
#define KK 25
#define WPB 16           // waves (queries) per block
#define TPB 1024
#define CAP 3072         // compacted-valid capacity (V ~ 2048 +- 32; P(V>CAP)~0)
#define SENT  0xFFFFFFFFFFFFFFFFull
#define SENTH 0xFFFFFFFFu   // exhausted marker for value words (> inf-bits+1)

// Wave64 min-reduce -> wave-uniform scalar (proven round-9 DPP ladder).
// Used by the (rare) serial-extraction fallback only.
static __device__ __forceinline__ u32 wave_min_u32(u32 x) {
    u32 t;
    t = (u32)__builtin_amdgcn_update_dpp(0, (int)x, 0xB1, 0xF, 0xF, true);   // xor1
    x = t < x ? t : x;
    t = (u32)__builtin_amdgcn_update_dpp(0, (int)x, 0x4E, 0xF, 0xF, true);   // xor2
    x = t < x ? t : x;
    t = (u32)__builtin_amdgcn_update_dpp(0, (int)x, 0x141, 0xF, 0xF, true);  // half-row mirror
    x = t < x ? t : x;
    t = (u32)__builtin_amdgcn_update_dpp(0, (int)x, 0x140, 0xF, 0xF, true);  // row mirror
    x = t < x ? t : x;
    t = (u32)__builtin_amdgcn_update_dpp((int)x, (int)x, 0x142, 0xF, 0xF, false); // row_bcast15
    x = t < x ? t : x;
    t = (u32)__builtin_amdgcn_update_dpp((int)x, (int)x, 0x143, 0xF, 0xF, false); // row_bcast31
    x = t < x ? t : x;
    return (u32)__builtin_amdgcn_readlane((int)x, 63);
}

// Ascending wave64 bitonic sort, one 32-bit key per lane (21 stages).
// Canonical form: dir = ((e & k) == 0); final merge k=64 -> all ascending.
static __device__ __forceinline__ u32 sort64_u32(u32 key, int lane) {
#pragma unroll
    for (int k = 2; k <= 64; k <<= 1) {
#pragma unroll
        for (int j = k >> 1; j >= 1; j >>= 1) {
            const u32 o = (u32)__shfl_xor((int)key, j, 64);
            const bool takeMin = ((lane & k) == 0) == ((lane & j) == 0);
            const u32 mn = o < key ? o : key;
            const u32 mx = o < key ? key : o;
            key = takeMin ? mn : mx;
        }
    }
    return key;
}

// Ascending wave64 bitonic sort, one 64-bit key per lane (21 stages).
static __device__ __forceinline__ u64 sort64_u64(u64 key, int lane) {
#pragma unroll
    for (int k = 2; k <= 64; k <<= 1) {
#pragma unroll
        for (int j = k >> 1; j >= 1; j >>= 1) {
            const u32 olo = (u32)__shfl_xor((int)(u32)key, j, 64);
            const u32 ohi = (u32)__shfl_xor((int)(u32)(key >> 32), j, 64);
            const u64 o = ((u64)ohi << 32) | olo;
            const bool takeMin = ((lane & k) == 0) == ((lane & j) == 0);
            const u64 mn = o < key ? o : key;
            const u64 mx = o < key ? key : o;
            key = takeMin ? mn : mx;
        }
    }
    return key;
}

// ROUND 22 = r19 staging+main (24.6us, stub-measured) + parallel selection
// replacing the 25-pop serial ladder (r20/21 measurement: extraction ~23.4us
// but only ~10us issue -> latency-bound serial chain; cutting ops could
// never fix it, removing the serial structure can):
//  1) sort 64 h1 value-words -> T = 25th-smallest lane-min (upper bound on
//     the true 25th key since pool superset of h1s).
//  2) prune to survivors (h_i <= T; downward-closed in key order so
//     rank-among-survivors == global rank; >=25 guaranteed), wave-scan
//     scatter to LDS (<=64 else rare fallback), read back 1/lane.
//  3) sort 64 survivor u64 keys -> ranks 0..24 in-register at lanes 0..24.
//  4) completeness: __any(lref < K25) (a lane's 4 kept all rank <25 => its
//     discarded 5th might belong) -> wave-uniform fallback = r19's proven
//     serial loop (h1..h4/J/lref intact; winners write u64 to sExt).
// Tie semantics: exact u64 (value,slot) key order everywhere == r19 pops.
__global__ void __launch_bounds__(TPB, 8) knn_kernel(
    const float* __restrict__ CB, const float* __restrict__ maskA,
    const float* __restrict__ Y, const int* __restrict__ Yt,
    const int* __restrict__ Ym, float* __restrict__ out)
{
    __shared__ __align__(16) float sX[CAP];   // 12 KiB each
    __shared__ __align__(16) float sY[CAP];
    __shared__ __align__(16) float sZ[CAP];
    __shared__ u16 sP16[CAP];                 // slot -> global p (6 KiB)
    __shared__ u16 sMidx[64];                 // first 64 masked indices (p order)
    __shared__ int sWinc[16];
    __shared__ int sWbase[16];
    __shared__ int sVtot;
    __shared__ u64 sExt[WPB][64];             // survivors / fallback winners (8 KiB)

    const int tid  = threadIdx.x;
    const int lane = tid & 63;
    const int wv   = tid >> 6;
    const int blk  = blockIdx.x;
    const int b    = blk >> 7;        // 128 blocks per batch (LL/WPB)
    const int qg   = blk & 127;

    const float* Yb  = Y  + (size_t)b * MM * 3;
    const int*   Ymb = Ym + (size_t)b * MM;
    const int*   Ytb = Yt + (size_t)b * MM;

    // ---- staging: stable compaction of valid candidates (r16, proven) ----
    const int p0 = tid << 2;
    const float4 f0 = *(const float4*)(Yb + 3 * p0);
    const float4 f1 = *(const float4*)(Yb + 3 * p0 + 4);
    const float4 f2 = *(const float4*)(Yb + 3 * p0 + 8);
    const int4   m4 = *(const int4*)(Ymb + p0);
    const int v0 = (m4.x != 0), v1 = (m4.y != 0), v2 = (m4.z != 0), v3 = (m4.w != 0);
    const int cnt0 = v0 + v1 + v2 + v3;

    int inc = cnt0;
#pragma unroll
    for (int off = 1; off < 64; off <<= 1) {
        const int t = __shfl_up(inc, off, 64);
        if (lane >= off) inc += t;
    }
    if (lane == 63) sWinc[wv] = inc;
    __syncthreads();
    if (tid < 16) {
        const int x = sWinc[tid];
        int ix = x;
#pragma unroll
        for (int off = 1; off < 16; off <<= 1) {
            const int t = __shfl_up(ix, off, 16);
            if (tid >= off) ix += t;
        }
        sWbase[tid] = ix - x;
        if (tid == 15) sVtot = ix;
    }
    __syncthreads();

    {
        int bs = sWbase[wv] + inc - cnt0;
        int mb = p0 - bs;
        if (v0) { sX[bs]=f0.x; sY[bs]=f0.y; sZ[bs]=f0.z; sP16[bs]=(u16)(p0+0); bs++; }
        else    { if (mb < 64) sMidx[mb] = (u16)(p0 + 0); mb++; }
        if (v1) { sX[bs]=f0.w; sY[bs]=f1.x; sZ[bs]=f1.y; sP16[bs]=(u16)(p0+1); bs++; }
        else    { if (mb < 64) sMidx[mb] = (u16)(p0 + 1); mb++; }
        if (v2) { sX[bs]=f1.z; sY[bs]=f1.w; sZ[bs]=f2.x; sP16[bs]=(u16)(p0+2); bs++; }
        else    { if (mb < 64) sMidx[mb] = (u16)(p0 + 2); mb++; }
        if (v3) { sX[bs]=f2.y; sY[bs]=f2.z; sZ[bs]=f2.w; sP16[bs]=(u16)(p0+3); bs++; }
        else    { if (mb < 64) sMidx[mb] = (u16)(p0 + 3); mb++; }
    }
    const int V  = sVtot;
    const int NJ = (V + 127) >> 7;
    for (int c = V + tid; c < (NJ << 7); c += TPB) {
        sX[c] = __builtin_inff(); sY[c] = 0.0f; sZ[c] = 0.0f; sP16[c] = 4095;
    }
    __syncthreads();

    const int l = qg * WPB + wv;
    const int q = b * LL + l;

    float* out_y = out;
    float* out_t = out + (size_t)BB * LL * KK * 3;
    float* out_m = out_t + (size_t)BB * LL * KK;
    float* out_d = out_m + (size_t)BB * LL * KK;

    // ---- fast path: masked query (verified r2..r19) ----
    if (maskA[q] == 0.0f) {
        if (lane < KK) {
            const int p = lane;
            const size_t o = (size_t)q * KK + lane;
            out_y[3 * o + 0] = Yb[3 * p + 0];
            out_y[3 * o + 1] = Yb[3 * p + 1];
            out_y[3 * o + 2] = Yb[3 * p + 2];
            out_t[o] = (float)Ytb[p];
            out_m[o] = (float)Ymb[p];
            if (lane == 0) out_d[q] = sqrtf(1000.0f);
        }
        return;
    }

    const float cx = CB[3 * q + 0];
    const float cy = CB[3 * q + 1];
    const float cz = CB[3 * q + 2];

    // ---- fused packed distance + per-lane stable top-4 (r19, proven) ----
    float v1f = 3.0e38f, v2f = 3.0e38f, v3f = 3.0e38f, v4f = 3.0e38f;
    u32 J = 0u;
    const u32 SEL1 = 0x06050400u;
    const u32 SEL2 = 0x06050004u;
    const u32 SEL3 = 0x06000504u;
    const u32 SEL4 = 0x00060504u;
    auto ins = [&](float v, u32 id) {
        const bool c1 = v < v1f, c2 = v < v2f, c3 = v < v3f, c4 = v < v4f;
        const u32 sel = c1 ? SEL1 : (c2 ? SEL2 : (c3 ? SEL3 : SEL4));
        const u32 Jp  = __builtin_amdgcn_perm(J, id, sel);
        const float n2 = __builtin_amdgcn_fmed3f(v, v1f, v2f);
        const float n3 = __builtin_amdgcn_fmed3f(v, v2f, v3f);
        const float n4 = __builtin_amdgcn_fmed3f(v, v3f, v4f);
        v1f = fminf(v, v1f);
        v2f = n2; v3f = n3; v4f = n4;
        J = c4 ? Jp : J;
    };

    const f32x2 cxx = {cx, cx}, cyy = {cy, cy}, czz = {cz, cz};
#pragma unroll 4
    for (int j = 0; j < NJ; ++j) {
        const int base = (j << 7) + (lane << 1);
        const f32x2 xp = *(const f32x2*)&sX[base];
        const f32x2 yp = *(const f32x2*)&sY[base];
        const f32x2 zp = *(const f32x2*)&sZ[base];
        const f32x2 dx = cxx - xp;
        const f32x2 dy = cyy - yp;
        const f32x2 dz = czz - zp;
        const f32x2 dsq = (dx * dx + dy * dy) + dz * dz;
        ins(dsq.x, (u32)(j << 1));
        ins(dsq.y, (u32)((j << 1) | 1));
    }

    auto slotof = [&](u32 id) -> u32 {
        return ((id >> 1) << 7) | (u32)(lane << 1) | (id & 1u);
    };

    const u32 s1 = slotof( J        & 0xFFu);
    const u32 s2 = slotof((J >>  8) & 0xFFu);
    const u32 s3 = slotof((J >> 16) & 0xFFu);
    const u32 s4 = slotof((J >> 24) & 0xFFu);
    u32 h1 = __float_as_uint(v1f) + 1u;
    u32 h2 = __float_as_uint(v2f) + 1u;
    u32 h3 = __float_as_uint(v3f) + 1u;
    u32 h4 = __float_as_uint(v4f) + 1u;
    u64 lref = ((u64)h4 << 32) | s4;     // lane's 4th-kept key (refill anchor)

    // ---- NEW: parallel selection (common path) ----
    bool fb = false;
    u64 myk = 0;
    {
        // T = 25th-smallest lane-min value-word (upper bound on true 25th)
        const u32 T = (u32)__builtin_amdgcn_readlane((int)sort64_u32(h1, lane), 24);
        const int c1 = (h1 <= T), c2 = (h2 <= T), c3 = (h3 <= T), c4 = (h4 <= T);
        const int cnt = c1 + c2 + c3 + c4;   // monotone h1<h2<h3<h4
        int incl = cnt;
#pragma unroll
        for (int off = 1; off < 64; off <<= 1) {
            const int t = __shfl_up(incl, off, 64);
            if (lane >= off) incl += t;
        }
        const int total = __builtin_amdgcn_readlane(incl, 63);   // wave-uniform
        if (total > 64) {
            fb = true;           // rare clustered case: serial fallback
        } else {
            u64* sE = sExt[wv];
            sE[lane] = SENT;                 // pad (sorts to the top)
            int pos = incl - cnt;            // exclusive base
            if (c1) { sE[pos] = ((u64)h1 << 32) | s1; pos++; }
            if (c2) { sE[pos] = ((u64)h2 << 32) | s2; pos++; }
            if (c3) { sE[pos] = ((u64)h3 << 32) | s3; pos++; }
            if (c4) { sE[pos] = ((u64)h4 << 32) | s4; pos++; }
            myk = sort64_u64(sE[lane], lane);   // rank `lane` key
            const u32 k25lo = (u32)__builtin_amdgcn_readlane((int)(u32)myk, 24);
            const u32 k25hi = (u32)__builtin_amdgcn_readlane((int)(u32)(myk >> 32), 24);
            const u64 K25 = ((u64)k25hi << 32) | k25lo;   // computed rank-24 key
            // pool-completeness: lane with all 4 kept below rank-24 might
            // have discarded a 5th that belongs -> fallback (over-triggers ok)
            if (__any(lref < K25)) fb = true;
        }
    }

    // ---- fallback: r19 serial extraction (proven), winners -> sExt ----
    if (fb) {
#pragma unroll 1
        for (int it = 0; it < KK; ++it) {
            if (it >= 4 && __any(h1 == SENTH)) {
                const bool need = (h1 == SENTH);
                u64 found = SENT;
                const int NI = NJ << 1;
#pragma unroll 4
                for (int id = 0; id < NI; ++id) {
                    const u32 s = slotof((u32)id);
                    const float dx = cx - sX[s];
                    const float dy = cy - sY[s];
                    const float dz = cz - sZ[s];
                    const float v = (dx * dx + dy * dy) + dz * dz;
                    const u64 key = ((u64)(__float_as_uint(v) + 1u) << 32) | s;
                    if (key > lref && key < found) found = key;
                }
                if (need) {
                    const u32 s = (u32)found & 0xFFFFu;
                    h1 = (u32)(found >> 32);
                    J = (J & ~0xFFu) | (((s >> 7) << 1) | (s & 1u));
                    lref = found;
                }
            }
            const u32 bv = wave_min_u32(h1);
            const u64 ball = __ballot(h1 == bv);
            bool win = (h1 == bv);
            if (__popcll(ball) != 1) {        // exact value tie: min slot wins
                const u32 vl = slotof(J & 0xFFu);
                u32 cp = win ? vl : 0xFFFFFFFFu;
#pragma unroll
                for (int off = 32; off; off >>= 1) {
                    const u32 o = __shfl_xor(cp, off, 64);
                    cp = (o < cp) ? o : cp;
                }
                win = win && (vl == cp);
            }
            if (win) {
                sExt[wv][it] = ((u64)h1 << 32) | slotof(J & 0xFFu);
                h1 = h2; h2 = h3; h3 = h4; h4 = SENTH;
                J >>= 8;
            }
        }
        if (lane < KK) myk = sExt[wv][lane];
    }

    // ---- merge valid winners with the constant masked run, then output ----
    const u32 mvh   = (u32)(myk >> 32);
    const u32 mslot = (u32)myk & 0xFFFFu;
    const bool less = (lane < KK) && (mvh < 0x447A0001u);  // v < 1000.0f
    const int nless = __popcll(__ballot(less));
    if (lane < KK) {
        int p; float val, mflag;
        if (lane < nless) {
            p = (int)sP16[mslot];
            val = __uint_as_float(mvh - 1u);
            mflag = 1.0f;
        } else {
            p = (int)sMidx[lane - nless];
            val = 1000.0f;
            mflag = 0.0f;
        }
        const size_t o = (size_t)q * KK + lane;
        out_y[3 * o + 0] = Yb[3 * p + 0];
        out_y[3 * o + 1] = Yb[3 * p + 1];
        out_y[3 * o + 2] = Yb[3 * p + 2];
        out_t[o] = (float)Ytb[p];
        out_m[o] = mflag;
        if (lane == 0) out_d[q] = sqrtf(val);
    }
}

extern "C" void kernel_launch(void* const* d_in, const int* in_sizes, int n_in,
                              void* d_out, int out_size, void* d_ws, size_t ws_size,
                              hipStream_t stream) {
    const float* CB   = (const float*)d_in[0];
    const float* mask = (const float*)d_in[1];
    const float* Y    = (const float*)d_in[2];
    const int*   Yt   = (const int*)d_in[3];
    const int*   Ym   = (const int*)d_in[4];
    float* out = (float*)d_out;

    dim3 grid(BB * LL / WPB);
    dim3 block(TPB);
    hipLaunchKernelGGL(knn_kernel, grid, block, 0, stream, CB, mask, Y, Yt, Ym, out);
}

// Round 12
// 103.680 us; speedup vs baseline: 1.8388x; 1.0381x over previous
//
#include <hip/hip_runtime.h>

// Forbid FMA contraction EVERYWHERE: distances must be bit-identical to
// numpy's unfused ((dx*dx + dy*dy) + dz*dz) in main loop AND fallback.
#pragma clang fp contract(off)

typedef unsigned long long u64;
typedef unsigned int u32;
typedef unsigned short u16;
typedef float f32x2 __attribute__((ext_vector_type(2)));

#define BB 8
#define LL 2048
#define MM 4096
#define KK 25
#define WPB 16           // waves (queries) per block
#define TPB 1024
#define CAP 3072         // compacted-valid capacity (V ~ 2048 +- 32; P(V>CAP)~0)
#define SENT  0xFFFFFFFFFFFFFFFFull
#define SENTH 0xFFFFFFFFu   // exhausted marker for value words (> inf-bits+1)

// Wave64 min-reduce -> wave-uniform scalar (proven round-9 DPP ladder).
static __device__ __forceinline__ u32 wave_min_u32(u32 x) {
    u32 t;
    t = (u32)__builtin_amdgcn_update_dpp(0, (int)x, 0xB1, 0xF, 0xF, true);   // xor1
    x = t < x ? t : x;
    t = (u32)__builtin_amdgcn_update_dpp(0, (int)x, 0x4E, 0xF, 0xF, true);   // xor2
    x = t < x ? t : x;
    t = (u32)__builtin_amdgcn_update_dpp(0, (int)x, 0x141, 0xF, 0xF, true);  // half-row mirror
    x = t < x ? t : x;
    t = (u32)__builtin_amdgcn_update_dpp(0, (int)x, 0x140, 0xF, 0xF, true);  // row mirror
    x = t < x ? t : x;
    t = (u32)__builtin_amdgcn_update_dpp((int)x, (int)x, 0x142, 0xF, 0xF, false); // row_bcast15
    x = t < x ? t : x;
    t = (u32)__builtin_amdgcn_update_dpp((int)x, (int)x, 0x143, 0xF, 0xF, false); // row_bcast31
    x = t < x ? t : x;
    return (u32)__builtin_amdgcn_readlane((int)x, 63);
}

// ROUND 23 = r22's structure with the selection rebuilt around FLAT
// primitives (r22 post-mortem: 21+21-stage bitonic shuffle nets are
// latency-bound like the serial ladder they replaced; depth is the cost):
//  * T = wave_min(h4) (6-step DPP ladder) replaces the 21-stage u32 sort.
//    Correctness: survivors<25 leaves sR[24]=SENT and lref<SENT always
//    fires the fallback; T<pool-K25 <=> some lane's h4 < K25 <=> the
//    existing __any(lref<K25) check. One check covers all failure modes.
//  * scatter positions from 4 ballot+popc (flat) instead of shfl_up scan.
//  * rank = #(survivors < mine) via ~40 BROADCAST LDS reads (uniform addr,
//    pipelined, zero serial cross-lane depth) instead of a 21-stage u64
//    sort. Ranks 0..24 scatter to sR; lanes 0..24 read winners.
//  * main loop: 4 cand/lane via ds_read_b128 (slot=(j<<8)|(lane<<2)|sub),
//    NJ~8, unroll 2 (window 6 b128 = 24 VGPR; r13 spill lesson).
// Fallback = r19 serial extraction verbatim (~5% of waves). Tie semantics:
// exact u64 (value,slot) order everywhere == proven pop order.
__global__ void __launch_bounds__(TPB, 8) knn_kernel(
    const float* __restrict__ CB, const float* __restrict__ maskA,
    const float* __restrict__ Y, const int* __restrict__ Yt,
    const int* __restrict__ Ym, float* __restrict__ out)
{
    __shared__ __align__(16) float sX[CAP];   // 12 KiB each
    __shared__ __align__(16) float sY[CAP];
    __shared__ __align__(16) float sZ[CAP];
    __shared__ u16 sP16[CAP];                 // slot -> global p (6 KiB)
    __shared__ u16 sMidx[64];                 // first 64 masked indices (p order)
    __shared__ int sWinc[16];
    __shared__ int sWbase[16];
    __shared__ int sVtot;
    __shared__ u64 sExt[WPB][64];             // survivors / fallback winners (8 KiB)
    __shared__ u64 sR[WPB][KK];               // rank->key (3.2 KiB)

    const int tid  = threadIdx.x;
    const int lane = tid & 63;
    const int wv   = tid >> 6;
    const int blk  = blockIdx.x;
    const int b    = blk >> 7;        // 128 blocks per batch (LL/WPB)
    const int qg   = blk & 127;

    const float* Yb  = Y  + (size_t)b * MM * 3;
    const int*   Ymb = Ym + (size_t)b * MM;
    const int*   Ytb = Yt + (size_t)b * MM;

    // ---- staging: stable compaction of valid candidates (r16, proven) ----
    const int p0 = tid << 2;
    const float4 f0 = *(const float4*)(Yb + 3 * p0);
    const float4 f1 = *(const float4*)(Yb + 3 * p0 + 4);
    const float4 f2 = *(const float4*)(Yb + 3 * p0 + 8);
    const int4   m4 = *(const int4*)(Ymb + p0);
    const int v0 = (m4.x != 0), v1 = (m4.y != 0), v2 = (m4.z != 0), v3 = (m4.w != 0);
    const int cnt0 = v0 + v1 + v2 + v3;

    int inc = cnt0;
#pragma unroll
    for (int off = 1; off < 64; off <<= 1) {
        const int t = __shfl_up(inc, off, 64);
        if (lane >= off) inc += t;
    }
    if (lane == 63) sWinc[wv] = inc;
    __syncthreads();
    if (tid < 16) {
        const int x = sWinc[tid];
        int ix = x;
#pragma unroll
        for (int off = 1; off < 16; off <<= 1) {
            const int t = __shfl_up(ix, off, 16);
            if (tid >= off) ix += t;
        }
        sWbase[tid] = ix - x;
        if (tid == 15) sVtot = ix;
    }
    __syncthreads();

    {
        int bs = sWbase[wv] + inc - cnt0;
        int mb = p0 - bs;
        if (v0) { sX[bs]=f0.x; sY[bs]=f0.y; sZ[bs]=f0.z; sP16[bs]=(u16)(p0+0); bs++; }
        else    { if (mb < 64) sMidx[mb] = (u16)(p0 + 0); mb++; }
        if (v1) { sX[bs]=f0.w; sY[bs]=f1.x; sZ[bs]=f1.y; sP16[bs]=(u16)(p0+1); bs++; }
        else    { if (mb < 64) sMidx[mb] = (u16)(p0 + 1); mb++; }
        if (v2) { sX[bs]=f1.z; sY[bs]=f1.w; sZ[bs]=f2.x; sP16[bs]=(u16)(p0+2); bs++; }
        else    { if (mb < 64) sMidx[mb] = (u16)(p0 + 2); mb++; }
        if (v3) { sX[bs]=f2.y; sY[bs]=f2.z; sZ[bs]=f2.w; sP16[bs]=(u16)(p0+3); bs++; }
        else    { if (mb < 64) sMidx[mb] = (u16)(p0 + 3); mb++; }
    }
    const int V  = sVtot;
    const int NJ = (V + 255) >> 8;            // 256-slot blocks (~8)
    for (int c = V + tid; c < (NJ << 8); c += TPB) {
        sX[c] = __builtin_inff(); sY[c] = 0.0f; sZ[c] = 0.0f; sP16[c] = 4095;
    }
    __syncthreads();

    const int l = qg * WPB + wv;
    const int q = b * LL + l;

    float* out_y = out;
    float* out_t = out + (size_t)BB * LL * KK * 3;
    float* out_m = out_t + (size_t)BB * LL * KK;
    float* out_d = out_m + (size_t)BB * LL * KK;

    // ---- fast path: masked query (verified r2..r22) ----
    if (maskA[q] == 0.0f) {
        if (lane < KK) {
            const int p = lane;
            const size_t o = (size_t)q * KK + lane;
            out_y[3 * o + 0] = Yb[3 * p + 0];
            out_y[3 * o + 1] = Yb[3 * p + 1];
            out_y[3 * o + 2] = Yb[3 * p + 2];
            out_t[o] = (float)Ytb[p];
            out_m[o] = (float)Ymb[p];
            if (lane == 0) out_d[q] = sqrtf(1000.0f);
        }
        return;
    }

    const float cx = CB[3 * q + 0];
    const float cy = CB[3 * q + 1];
    const float cz = CB[3 * q + 2];

    // ---- fused packed distance + per-lane stable top-4 (asc by (v,slot)) --
    float v1f = 3.0e38f, v2f = 3.0e38f, v3f = 3.0e38f, v4f = 3.0e38f;
    u32 J = 0u;                     // byte-packed ids id=(j<<2)|sub
    const u32 SEL1 = 0x06050400u;
    const u32 SEL2 = 0x06050004u;
    const u32 SEL3 = 0x06000504u;
    const u32 SEL4 = 0x00060504u;
    auto ins = [&](float v, u32 id) {
        const bool c1 = v < v1f, c2 = v < v2f, c3 = v < v3f, c4 = v < v4f;
        const u32 sel = c1 ? SEL1 : (c2 ? SEL2 : (c3 ? SEL3 : SEL4));
        const u32 Jp  = __builtin_amdgcn_perm(J, id, sel);
        const float n2 = __builtin_amdgcn_fmed3f(v, v1f, v2f);
        const float n3 = __builtin_amdgcn_fmed3f(v, v2f, v3f);
        const float n4 = __builtin_amdgcn_fmed3f(v, v3f, v4f);
        v1f = fminf(v, v1f);
        v2f = n2; v3f = n3; v4f = n4;
        J = c4 ? Jp : J;
    };

    const f32x2 cxx = {cx, cx}, cyy = {cy, cy}, czz = {cz, cz};
#pragma unroll 2
    for (int j = 0; j < NJ; ++j) {
        const int base = (j << 8) + (lane << 2);
        const float4 xq = *(const float4*)&sX[base];
        const float4 yq = *(const float4*)&sY[base];
        const float4 zq = *(const float4*)&sZ[base];
        f32x2 dx = cxx - f32x2{xq.x, xq.y};
        f32x2 dy = cyy - f32x2{yq.x, yq.y};
        f32x2 dz = czz - f32x2{zq.x, zq.y};
        const f32x2 d01 = (dx * dx + dy * dy) + dz * dz;
        dx = cxx - f32x2{xq.z, xq.w};
        dy = cyy - f32x2{yq.z, yq.w};
        dz = czz - f32x2{zq.z, zq.w};
        const f32x2 d23 = (dx * dx + dy * dy) + dz * dz;
        ins(d01.x, (u32)(j << 2));
        ins(d01.y, (u32)((j << 2) | 1));
        ins(d23.x, (u32)((j << 2) | 2));
        ins(d23.y, (u32)((j << 2) | 3));
    }

    auto slotof = [&](u32 id) -> u32 {
        return ((id >> 2) << 8) | (u32)(lane << 2) | (id & 3u);
    };

    const u32 s1 = slotof( J        & 0xFFu);
    const u32 s2 = slotof((J >>  8) & 0xFFu);
    const u32 s3 = slotof((J >> 16) & 0xFFu);
    const u32 s4 = slotof((J >> 24) & 0xFFu);
    u32 h1 = __float_as_uint(v1f) + 1u;
    u32 h2 = __float_as_uint(v2f) + 1u;
    u32 h3 = __float_as_uint(v3f) + 1u;
    u32 h4 = __float_as_uint(v4f) + 1u;
    u64 lref = ((u64)h4 << 32) | s4;     // lane's 4th-kept key (refill anchor)

    // ---- flat parallel selection (common path) ----
    bool fb = false;
    u64 myk = 0;
    {
        const u32 T = wave_min_u32(h4);   // wave-uniform; depth-6 DPP ladder
        const bool c1 = (h1 <= T), c2 = (h2 <= T), c3 = (h3 <= T), c4 = (h4 <= T);
        const u64 b1 = __ballot(c1), b2 = __ballot(c2);
        const u64 b3 = __ballot(c3), b4 = __ballot(c4);
        const int n1 = __popcll(b1), n2 = __popcll(b2), n3 = __popcll(b3);
        const int total = n1 + n2 + n3 + __popcll(b4);
        if (total > 64) {
            fb = true;                    // rare clustered case
        } else {
            const u64 below = (1ull << lane) - 1ull;
            u64* sE = sExt[wv];
            sE[lane] = SENT;              // pad [total,64)
            if (lane == 24) sR[wv][24] = SENT;   // incomplete-detector
            int pos = __popcll(b1 & below);
            if (c1) sE[pos] = ((u64)h1 << 32) | s1;
            pos = n1 + __popcll(b2 & below);
            if (c2) sE[pos] = ((u64)h2 << 32) | s2;
            pos = n1 + n2 + __popcll(b3 & below);
            if (c3) sE[pos] = ((u64)h3 << 32) | s3;
            pos = n1 + n2 + n3 + __popcll(b4 & below);
            if (c4) sE[pos] = ((u64)h4 << 32) | s4;
            const u64 mk = sE[lane];
            // rank = #(survivors < mine): broadcast reads, zero serial depth
            int rank = 0;
            const int tot = (total + 7) & ~7;
#pragma unroll 8
            for (int i = 0; i < tot; ++i)
                rank += (sE[i] < mk) ? 1 : 0;
            if (rank < KK && mk != SENT) sR[wv][rank] = mk;
            const u64 K25 = sR[wv][24];   // broadcast; SENT if survivors<25
            // pool/prune completeness (covers T<pool-K25 and survivors<25):
            if (__any(lref < K25)) fb = true;
            else if (lane < KK) myk = sR[wv][lane];
        }
    }

    // ---- fallback: r19 serial extraction (proven), winners -> sExt ----
    if (fb) {
#pragma unroll 1
        for (int it = 0; it < KK; ++it) {
            if (it >= 4 && __any(h1 == SENTH)) {
                const bool need = (h1 == SENTH);
                u64 found = SENT;
                const int NI = NJ << 2;
#pragma unroll 4
                for (int id = 0; id < NI; ++id) {
                    const u32 s = slotof((u32)id);
                    const float dx = cx - sX[s];
                    const float dy = cy - sY[s];
                    const float dz = cz - sZ[s];
                    const float v = (dx * dx + dy * dy) + dz * dz;
                    const u64 key = ((u64)(__float_as_uint(v) + 1u) << 32) | s;
                    if (key > lref && key < found) found = key;
                }
                if (need) {
                    const u32 s = (u32)found & 0xFFFFu;
                    h1 = (u32)(found >> 32);
                    J = (J & ~0xFFu) | (((s >> 8) << 2) | (s & 3u));
                    lref = found;
                }
            }
            const u32 bv = wave_min_u32(h1);
            const u64 ball = __ballot(h1 == bv);
            bool win = (h1 == bv);
            if (__popcll(ball) != 1) {        // exact value tie: min slot wins
                const u32 vl = slotof(J & 0xFFu);
                u32 cp = win ? vl : 0xFFFFFFFFu;
#pragma unroll
                for (int off = 32; off; off >>= 1) {
                    const u32 o = __shfl_xor(cp, off, 64);
                    cp = (o < cp) ? o : cp;
                }
                win = win && (vl == cp);
            }
            if (win) {
                sExt[wv][it] = ((u64)h1 << 32) | slotof(J & 0xFFu);
                h1 = h2; h2 = h3; h3 = h4; h4 = SENTH;
                J >>= 8;
            }
        }
        if (lane < KK) myk = sExt[wv][lane];
    }

    // ---- merge valid winners with the constant masked run, then output ----
    const u32 mvh   = (u32)(myk >> 32);
    const u32 mslot = (u32)myk & 0xFFFFu;
    const bool less = (lane < KK) && (mvh < 0x447A0001u);  // v < 1000.0f
    const int nless = __popcll(__ballot(less));
    if (lane < KK) {
        int p; float val, mflag;
        if (lane < nless) {
            p = (int)sP16[mslot];
            val = __uint_as_float(mvh - 1u);
            mflag = 1.0f;
        } else {
            p = (int)sMidx[lane - nless];
            val = 1000.0f;
            mflag = 0.0f;
        }
        const size_t o = (size_t)q * KK + lane;
        out_y[3 * o + 0] = Yb[3 * p + 0];
        out_y[3 * o + 1] = Yb[3 * p + 1];
        out_y[3 * o + 2] = Yb[3 * p + 2];
        out_t[o] = (float)Ytb[p];
        out_m[o] = mflag;
        if (lane == 0) out_d[q] = sqrtf(val);
    }
}

extern "C" void kernel_launch(void* const* d_in, const int* in_sizes, int n_in,
                              void* d_out, int out_size, void* d_ws, size_t ws_size,
                              hipStream_t stream) {
    const float* CB   = (const float*)d_in[0];
    const float* mask = (const float*)d_in[1];
    const float* Y    = (const float*)d_in[2];
    const int*   Yt   = (const int*)d_in[3];
    const int*   Ym   = (const int*)d_in[4];
    float* out = (float*)d_out;

    dim3 grid(BB * LL / WPB);
    dim3 block(TPB);
    hipLaunchKernelGGL(knn_kernel, grid, block, 0, stream, CB, mask, Y, Yt, Ym, out);
}